// Round 18
// baseline (284.166 us; speedup 1.0000x reference)
//
#include <hip/hip_runtime.h>
#include <math.h>

#define NN    4096
#define CIN   128
#define CO    128
#define HD    512
#define KK    20
#define EE    21
#define EDGES (NN * EE)   // 86016
#define LNEPS 1e-5f
#define WSZ   65536       // elems per weight matrix (128*512)

typedef unsigned short u16;
typedef unsigned int   u32;
typedef unsigned long long u64;
typedef __attribute__((ext_vector_type(8))) short bf16x8;
typedef __attribute__((ext_vector_type(4))) float f32x4;

#define MFMA16(a,b,c) __builtin_amdgcn_mfma_f32_16x16x32_bf16(a,b,c,0,0,0)

__device__ __forceinline__ u16 f2b(float x) {
    u32 u = __float_as_uint(x);
    u32 r = u + 0x7fffu + ((u >> 16) & 1u);   // round-to-nearest-even
    return (u16)(r >> 16);
}
__device__ __forceinline__ float b2f(u16 h) {
    return __uint_as_float(((u32)h) << 16);
}
// packed 2xf32 -> 2xbf16 (RNE), 1 VALU op
__device__ __forceinline__ u32 cvtpk(float lo, float hi) {
    u32 r;
    asm("v_cvt_pk_bf16_f32 %0, %1, %2" : "=v"(r) : "v"(lo), "v"(hi));
    return r;
}

// ---------------- LayerNorm + ELU on bf16 rows (L=512), NW waves, cvt_pk packed ----------------
template<int L, int NW>
__device__ __forceinline__ void ln_elu_b16(u16* base, int rows, int stride,
        const float* __restrict__ gam, const float* __restrict__ bet)
{
    constexpr int P = L / 64;     // 8 contiguous elems per lane
    static_assert(P == 8, "packed path assumes P==8");
    int t = threadIdx.x, lane = t & 63, w = t >> 6;
    float g[P], b[P];
#pragma unroll
    for (int q = 0; q < P; q += 4) {
        *(float4*)&g[q] = *(const float4*)&gam[lane*P + q];
        *(float4*)&b[q] = *(const float4*)&bet[lane*P + q];
    }
    for (int e = w; e < rows; e += NW) {
        u16* row = base + e*stride + lane*P;
        uint4 rp = *(const uint4*)row;            // 1x ds_read_b128
        float vals[P];
        vals[0] = __uint_as_float(rp.x << 16); vals[1] = __uint_as_float(rp.x & 0xffff0000u);
        vals[2] = __uint_as_float(rp.y << 16); vals[3] = __uint_as_float(rp.y & 0xffff0000u);
        vals[4] = __uint_as_float(rp.z << 16); vals[5] = __uint_as_float(rp.z & 0xffff0000u);
        vals[6] = __uint_as_float(rp.w << 16); vals[7] = __uint_as_float(rp.w & 0xffff0000u);
        float s = 0.f, sq = 0.f;
#pragma unroll
        for (int q = 0; q < P; ++q) { s += vals[q]; sq = fmaf(vals[q], vals[q], sq); }
#pragma unroll
        for (int off = 32; off > 0; off >>= 1) {
            s  += __shfl_xor(s,  off, 64);
            sq += __shfl_xor(sq, off, 64);
        }
        float mn = s * (1.0f / L);
        float msq = mn * mn;
        float var = fmaf(sq, 1.0f / L, -msq);     // pinned contraction
        float rstd = rsqrtf(var + LNEPS);
        float yv[P];
#pragma unroll
        for (int q = 0; q < P; ++q) {
            float z = (vals[q] - mn) * rstd;
            float y = fmaf(z, g[q], b[q]);        // pinned
            yv[q] = y > 0.f ? y : __expf(y) - 1.f;
        }
        uint4 wp;
        wp.x = cvtpk(yv[0], yv[1]); wp.y = cvtpk(yv[2], yv[3]);
        wp.z = cvtpk(yv[4], yv[5]); wp.w = cvtpk(yv[6], yv[7]);
        *(uint4*)row = wp;                        // 1x ds_write_b128
    }
}

// ---------------- LayerNorm + ELU on f32 rows (L=128), NW waves, pinned FMA ----------------
template<int L, int NW>
__device__ __forceinline__ void ln_elu_f32v(float* base, int rows, int stride,
        const float* __restrict__ gam, const float* __restrict__ bet)
{
    constexpr int P = L / 64;     // 2
    int t = threadIdx.x, lane = t & 63, w = t >> 6;
    float g[P], b[P];
    *(float2*)&g[0] = *(const float2*)&gam[lane*P];
    *(float2*)&b[0] = *(const float2*)&bet[lane*P];
    for (int e = w; e < rows; e += NW) {
        float* row = base + e*stride + lane*P;
        float vals[P];
        *(float2*)&vals[0] = *(const float2*)&row[0];
        float s = 0.f, sq = 0.f;
#pragma unroll
        for (int q = 0; q < P; ++q) { s += vals[q]; sq = fmaf(vals[q], vals[q], sq); }
#pragma unroll
        for (int off = 32; off > 0; off >>= 1) {
            s  += __shfl_xor(s,  off, 64);
            sq += __shfl_xor(sq, off, 64);
        }
        float mn = s * (1.0f / L);
        float msq = mn * mn;
        float var = fmaf(sq, 1.0f / L, -msq);     // pinned contraction
        float rstd = rsqrtf(var + LNEPS);
#pragma unroll
        for (int q = 0; q < P; ++q) {
            float z = (vals[q] - mn) * rstd;
            float y = fmaf(z, g[q], b[q]);        // pinned
            vals[q] = y > 0.f ? y : __expf(y) - 1.f;
        }
        *(float2*)&row[0] = *(const float2*)&vals[0];
    }
}

// ---------------- fused prologue: knn (b<1024) | wconv3 (b<1792) | lin3 ----------------
__global__ __launch_bounds__(256) void k_pro(
        const float* __restrict__ pos, const float* __restrict__ x,
        const float* __restrict__ Wl, const float* __restrict__ Ws, const float* __restrict__ Wd,
        const float* __restrict__ aw1, const float* __restrict__ aw2,
        const float* __restrict__ pw2,
        int* __restrict__ idxg, float* __restrict__ v,
        float* __restrict__ as_, float* __restrict__ ad,
        u16* __restrict__ awp1, u16* __restrict__ awp2, u16* __restrict__ pwp2)
{
    __shared__ float sx[8][CIN];
    int b = blockIdx.x;
    if (b < 1024) {                 // ---- kNN: 4 nodes/block, 1 wave each ----
        int i = b * 4 + (threadIdx.x >> 6);
        int lane = threadIdx.x & 63;
        float px = pos[3*i], py = pos[3*i+1], pz = pos[3*i+2];
        float bd[KK]; int bi[KK];
#pragma unroll
        for (int s = 0; s < KK; ++s) { bd[s] = INFINITY; bi[s] = 0x7fffffff; }
        for (int j = lane; j < NN; j += 64) {
            float dx = px - pos[3*j], dy = py - pos[3*j+1], dz = pz - pos[3*j+2];
            float d2 = dx*dx + dy*dy + dz*dz;
            if (j != i && d2 < bd[KK-1]) {
                float cd = d2; int ci = j;
#pragma unroll
                for (int s = 0; s < KK; ++s) {   // static-index bubble insert
                    bool sw = cd < bd[s];
                    float td = sw ? bd[s] : cd;  int ti = sw ? bi[s] : ci;
                    bd[s] = sw ? cd : bd[s];     bi[s] = sw ? ci : bi[s];
                    cd = td; ci = ti;
                }
            }
        }
        for (int r = 0; r < KK; ++r) {
            u64 m = ~0ull;
#pragma unroll
            for (int s = 0; s < KK; ++s) {
                u64 k = ((u64)__float_as_uint(bd[s]) << 32) | (u32)bi[s];
                m = k < m ? k : m;
            }
#pragma unroll
            for (int off = 32; off > 0; off >>= 1) {
                u64 o = __shfl_xor(m, off, 64);
                m = o < m ? o : m;
            }
            if (lane == 0) idxg[i*EE + r] = (int)(u32)m;
#pragma unroll
            for (int s = 0; s < KK; ++s) {
                u64 k = ((u64)__float_as_uint(bd[s]) << 32) | (u32)bi[s];
                if (k == m) bd[s] = INFINITY;
            }
        }
        if (lane == 0) idxg[i*EE + KK] = i;   // self-loop appended
    } else if (b < 1792) {          // ---- weight prepack ----
        int gb = b - 1024;
        const float* src; u16* dst; int N, kplog, base; bool split;
        if (gb < 256)      { src = aw1; dst = awp1; N = HD; kplog = 2; base = 0;   split = false; }
        else if (gb < 512) { src = aw2; dst = awp2; N = CO; kplog = 4; base = 256; split = true;  }
        else               { src = pw2; dst = pwp2; N = CO; kplog = 4; base = 512; split = true;  }
        int idx = (gb - base)*256 + threadIdx.x;
        int j  = idx & 7;
        int l  = (idx >> 3) & 63;
        int ks = (idx >> 9) & ((1 << kplog) - 1);
        int nt = idx >> (9 + kplog);
        int k = ks*32 + (l >> 4)*8 + j;
        int c = nt*16 + (l & 15);
        float w = src[(size_t)k*N + c];
        u16 hi = f2b(w);
        dst[idx] = hi;
        if (split) dst[idx + WSZ] = f2b(w - b2f(hi));
    } else {                        // ---- lin3: v / a_src / a_dst, 8 nodes/block ----
        int bb = b - 1792, t = threadIdx.x;
        int n0 = bb * 8;
        for (int q = t; q < 8*CIN; q += 256) sx[q >> 7][q & 127] = x[n0*CIN + q];
        __syncthreads();
        int c = t & 127, g = t >> 7;
        float al[4] = {0,0,0,0}, asr[4] = {0,0,0,0}, adr[4] = {0,0,0,0};
        for (int k = 0; k < CIN; ++k) {
            float wl = Wl[k*CO + c], ws = Ws[k*CO + c], wd = Wd[k*CO + c];
#pragma unroll
            for (int nn2 = 0; nn2 < 4; ++nn2) {
                float xv = sx[g*4 + nn2][k];
                al[nn2]  = fmaf(xv, wl, al[nn2]);
                asr[nn2] = fmaf(xv, ws, asr[nn2]);
                adr[nn2] = fmaf(xv, wd, adr[nn2]);
            }
        }
#pragma unroll
        for (int nn2 = 0; nn2 < 4; ++nn2) {
            int n = n0 + g*4 + nn2;
            v[n*CO + c]   = al[nn2];
            as_[n*CO + c] = asr[nn2];
            ad[n*CO + c]  = adr[nn2];
        }
    }
}

// strides (padded)
#define SA_S 136   // u16, 128+8
#define SH_S 520   // u16, 512+8
#define SF_S 132   // f32, 128+4

// ---------------- fused MLP, single-buffer LDS (33.7 KB -> 4 blocks/CU) ----------------
// s_h region phases (all transitions: load-frags -> barrier -> overwrite):
//   P1 h(bf16) -> P2 frags loaded -> s_d(f32, bytes 0..16895)
//   -> alpha0(s_aH, bytes 16896..25599; reads s_d, disjoint)
//   -> A1 frags loaded -> A1 h(bf16, full region) -> A2 frags loaded
//   -> s_af(f32, bytes 0..16895) -> alphaF store
__global__ __launch_bounds__(512) void k_mlp(
        const float* __restrict__ pos, const int* __restrict__ idxg,
        const float* __restrict__ as_, const float* __restrict__ ad,
        const float* __restrict__ pw1, const float* __restrict__ pb1,
        const float* __restrict__ pg1, const float* __restrict__ pbt1,
        const u16* __restrict__ pwp2, const float* __restrict__ pb2,
        const float* __restrict__ pg2, const float* __restrict__ pbt2,
        const u16* __restrict__ awp1, const float* __restrict__ ab1,
        const float* __restrict__ ag1, const float* __restrict__ abt1,
        const u16* __restrict__ awp2, const float* __restrict__ ab2,
        const float* __restrict__ ag2, const float* __restrict__ abt2,
        u16* __restrict__ delta, u16* __restrict__ alphaF)
{
    __shared__ __align__(16) u16 s_h[32*SH_S];   // 33280 B (single buffer)
    __shared__ float s_rel[32][3];
    float* s_d  = (float*)s_h;                   // f32 staging, bytes 0..16895
    float* s_af = (float*)s_h;
    u16*   s_aH = s_h + 8448;                    // alpha0, bytes 16896..25599
    int t = threadIdx.x;
    int e0g = blockIdx.x * 32;
    if (t < 32) {
        int e = e0g + t;
        u32 ii = (u32)e / 21u;
        int j = idxg[e];
        s_rel[t][0] = pos[3*ii]   - pos[3*j];
        s_rel[t][1] = pos[3*ii+1] - pos[3*j+1];
        s_rel[t][2] = pos[3*ii+2] - pos[3*j+2];
    }
    __syncthreads();
    {   // P1: h = rel @ pw1 + pb1 (pinned fmaf chain; 1 channel/thread, cvt_pk pairs)
        int c1 = t;
        float wa0 = pw1[c1], wa1 = pw1[HD + c1], wa2 = pw1[2*HD + c1], ba = pb1[c1];
        for (int r = 0; r < 32; r += 2) {
            float h0 = fmaf(s_rel[r][2],   wa2, fmaf(s_rel[r][1],   wa1, fmaf(s_rel[r][0],   wa0, ba)));
            float h1 = fmaf(s_rel[r+1][2], wa2, fmaf(s_rel[r+1][1], wa1, fmaf(s_rel[r+1][0], wa0, ba)));
            u32 pk = cvtpk(h0, h1);
            s_h[r*SH_S + c1]     = (u16)pk;
            s_h[(r+1)*SH_S + c1] = (u16)(pk >> 16);
        }
    }
    __syncthreads();
    ln_elu_b16<HD, 8>(s_h, 32, SH_S, pg1, pbt1);
    __syncthreads();
    int w = t >> 6, l = t & 63, lr = l & 15, lk = l >> 4;
    int m = w & 1;
    {   // P2 (MFMA, split-weight, dual acc): load frags, barrier, write s_d over s_h
        int nt0 = (w >> 1) * 2;
        bf16x8 afr[16];
#pragma unroll
        for (int ks = 0; ks < 16; ++ks)
            afr[ks] = *(const bf16x8*)&s_h[(m*16 + lr)*SH_S + ks*32 + lk*8];
        __syncthreads();                          // all frags in regs; s_h writable
        f32x4 accs[2];
#pragma unroll
        for (int n2 = 0; n2 < 2; ++n2) {
            int nt = nt0 + n2;
            const u16* bp  = pwp2 + ((size_t)nt*16*64 + l)*8;
            const u16* bpl = bp + WSZ;
            f32x4 acch = {0.f, 0.f, 0.f, 0.f};
            f32x4 accl = {0.f, 0.f, 0.f, 0.f};
#pragma unroll
            for (int ks = 0; ks < 16; ++ks) {
                bf16x8 bh = *(const bf16x8*)(bp + ks*512);
                acch = MFMA16(afr[ks], bh, acch);
                bf16x8 bl = *(const bf16x8*)(bpl + ks*512);
                accl = MFMA16(afr[ks], bl, accl);
            }
            float bias = pb2[nt*16 + lr];
#pragma unroll
            for (int r = 0; r < 4; ++r)
                accs[n2][r] = (acch[r] + accl[r]) + bias;
        }
#pragma unroll
        for (int n2 = 0; n2 < 2; ++n2)
#pragma unroll
            for (int r = 0; r < 4; ++r)
                s_d[(m*16 + lk*4 + r)*SF_S + (nt0 + n2)*16 + lr] = accs[n2][r];
    }
    __syncthreads();
    ln_elu_f32v<CO, 8>(s_d, 32, SF_S, pg2, pbt2);
    __syncthreads();
    {   // delta store (bf16, cvt_pk) + alpha0 = ad[i] - as[j] + delta_f32 -> s_aH
        int el = t >> 4, c0 = (t & 15) << 3;
        int e = e0g + el;
        int i = (int)((u32)e / 21u);
        int j = idxg[e];
        const float* sp  = &s_d[el*SF_S + c0];
        float4 d0 = *(const float4*)(sp);
        float4 d1 = *(const float4*)(sp + 4);
        uint4 od;
        od.x = cvtpk(d0.x, d0.y); od.y = cvtpk(d0.z, d0.w);
        od.z = cvtpk(d1.x, d1.y); od.w = cvtpk(d1.z, d1.w);
        *(uint4*)&delta[(size_t)e*CO + c0] = od;
        const float* adp = ad  + i*CIN + c0;
        const float* asp = as_ + j*CIN + c0;
        float4 a0 = *(const float4*)(adp);
        float4 a1 = *(const float4*)(adp + 4);
        float4 s0 = *(const float4*)(asp);
        float4 s1 = *(const float4*)(asp + 4);
        uint4 oa;
        oa.x = cvtpk(a0.x - s0.x + d0.x, a0.y - s0.y + d0.y);
        oa.y = cvtpk(a0.z - s0.z + d0.z, a0.w - s0.w + d0.w);
        oa.z = cvtpk(a1.x - s1.x + d1.x, a1.y - s1.y + d1.y);
        oa.w = cvtpk(a1.z - s1.z + d1.z, a1.w - s1.w + d1.w);
        *(uint4*)&s_aH[el*SA_S + c0] = oa;       // disjoint from s_d bytes
    }
    __syncthreads();
    // A1 fragment loads from s_aH
    bf16x8 afr1[4];
#pragma unroll
    for (int ks = 0; ks < 4; ++ks)
        afr1[ks] = *(const bf16x8*)&s_aH[(m*16 + lr)*SA_S + ks*32 + lk*8];
    __syncthreads();   // all waves hold alpha0 fragments; full s_h writable
    {   // A1 (MFMA): [32,128]@[128,512]; 8 waves x 8 n-tiles -> s_h (bf16, cvt_pk pairs)
        int nt0 = (w >> 1) * 8;
#pragma unroll
        for (int n2 = 0; n2 < 8; ++n2) {
            int nt = nt0 + n2;
            const u16* bp = awp1 + ((size_t)nt*4*64 + l)*8;
            f32x4 acc = {0.f, 0.f, 0.f, 0.f};
#pragma unroll
            for (int ks = 0; ks < 4; ++ks) {
                bf16x8 bfr = *(const bf16x8*)(bp + ks*512);
                acc = MFMA16(afr1[ks], bfr, acc);
            }
            float bias = ab1[nt*16 + lr];
            u32 p01 = cvtpk(acc[0] + bias, acc[1] + bias);
            u32 p23 = cvtpk(acc[2] + bias, acc[3] + bias);
            int rb = (m*16 + lk*4)*SH_S + nt*16 + lr;
            s_h[rb]          = (u16)p01;
            s_h[rb + SH_S]   = (u16)(p01 >> 16);
            s_h[rb + 2*SH_S] = (u16)p23;
            s_h[rb + 3*SH_S] = (u16)(p23 >> 16);
        }
    }
    __syncthreads();
    ln_elu_b16<HD, 8>(s_h, 32, SH_S, ag1, abt1);
    __syncthreads();
    {   // A2 (MFMA, split-weight, dual acc): load frags, barrier, write s_af over s_h
        int nt0 = (w >> 1) * 2;
        bf16x8 afr[16];
#pragma unroll
        for (int ks = 0; ks < 16; ++ks)
            afr[ks] = *(const bf16x8*)&s_h[(m*16 + lr)*SH_S + ks*32 + lk*8];
        __syncthreads();                          // all frags in regs; s_h writable
        f32x4 accs[2];
#pragma unroll
        for (int n2 = 0; n2 < 2; ++n2) {
            int nt = nt0 + n2;
            const u16* bp  = awp2 + ((size_t)nt*16*64 + l)*8;
            const u16* bpl = bp + WSZ;
            f32x4 acch = {0.f, 0.f, 0.f, 0.f};
            f32x4 accl = {0.f, 0.f, 0.f, 0.f};
#pragma unroll
            for (int ks = 0; ks < 16; ++ks) {
                bf16x8 bh = *(const bf16x8*)(bp + ks*512);
                acch = MFMA16(afr[ks], bh, acch);
                bf16x8 bl = *(const bf16x8*)(bpl + ks*512);
                accl = MFMA16(afr[ks], bl, accl);
            }
            float bias = ab2[nt*16 + lr];
#pragma unroll
            for (int r = 0; r < 4; ++r)
                accs[n2][r] = (acch[r] + accl[r]) + bias;
        }
#pragma unroll
        for (int n2 = 0; n2 < 2; ++n2)
#pragma unroll
            for (int r = 0; r < 4; ++r)
                s_af[(m*16 + lk*4 + r)*SF_S + (nt0 + n2)*16 + lr] = accs[n2][r];
    }
    __syncthreads();
    ln_elu_f32v<CO, 8>(s_af, 32, SF_S, ag2, abt2);
    __syncthreads();
    {   // store alphaF: cvt_pk at the end only
        int el = t >> 4, c0 = (t & 15) << 3;
        const float* sp = &s_af[el*SF_S + c0];
        float4 v0 = *(const float4*)(sp);
        float4 v1 = *(const float4*)(sp + 4);
        uint4 o;
        o.x = cvtpk(v0.x, v0.y); o.y = cvtpk(v0.z, v0.w);
        o.z = cvtpk(v1.x, v1.y); o.w = cvtpk(v1.z, v1.w);
        *(uint4*)&alphaF[(size_t)(e0g + el)*CO + c0] = o;
    }
}

// ---------------- softmax over neighbors + weighted aggregate (4 nodes/block, 2 ch/thread) ----------------
__global__ __launch_bounds__(256) void k_agg(
        const int* __restrict__ idxg,
        const float* __restrict__ v, const u16* __restrict__ delta,
        const u16* __restrict__ alphaF, float* __restrict__ out)
{
    __shared__ int s_idx[4][EE];
    int b = blockIdx.x, t = threadIdx.x;
    int n0 = b * 4;
    if (t < 4*EE) s_idx[t/EE][t%EE] = idxg[n0*EE + t];
    __syncthreads();
    int g = t >> 6, c0 = (t & 63) * 2;
    int i = n0 + g;
    size_t base = (size_t)i*EE*CO + c0;
    float afx[EE], afy[EE];
    float mx0 = -INFINITY, mx1 = -INFINITY;
#pragma unroll
    for (int e = 0; e < EE; ++e) {
        ushort2 u = *(const ushort2*)&alphaF[base + e*CO];
        afx[e] = b2f(u.x); afy[e] = b2f(u.y);
        mx0 = fmaxf(mx0, afx[e]); mx1 = fmaxf(mx1, afy[e]);
    }
    float ss0 = 0.f, ss1 = 0.f;
#pragma unroll
    for (int e = 0; e < EE; ++e) {
        afx[e] = __expf(afx[e] - mx0); ss0 += afx[e];
        afy[e] = __expf(afy[e] - mx1); ss1 += afy[e];
    }
    float ac0 = 0.f, ac1 = 0.f;
#pragma unroll
    for (int e = 0; e < EE; ++e) {
        int j = s_idx[g][e];
        float2 vv = *(const float2*)&v[j*CO + c0];
        ushort2 dd = *(const ushort2*)&delta[base + e*CO];
        ac0 = fmaf(afx[e], vv.x + b2f(dd.x), ac0);
        ac1 = fmaf(afy[e], vv.y + b2f(dd.y), ac1);
    }
    float2 o; o.x = ac0 / ss0; o.y = ac1 / ss1;
    *(float2*)&out[i*CO + c0] = o;
}

extern "C" void kernel_launch(void* const* d_in, const int* in_sizes, int n_in,
                              void* d_out, int out_size, void* d_ws, size_t ws_size,
                              hipStream_t stream)
{
    const float* x    = (const float*)d_in[0];
    const float* pos  = (const float*)d_in[1];
    const float* Wl   = (const float*)d_in[3];
    const float* Wsrc = (const float*)d_in[4];
    const float* Wdst = (const float*)d_in[5];
    const float* pw1  = (const float*)d_in[6];
    const float* pb1  = (const float*)d_in[7];
    const float* pg1  = (const float*)d_in[8];
    const float* pbt1 = (const float*)d_in[9];
    const float* pw2  = (const float*)d_in[10];
    const float* pb2  = (const float*)d_in[11];
    const float* pg2  = (const float*)d_in[12];
    const float* pbt2 = (const float*)d_in[13];
    const float* aw1  = (const float*)d_in[14];
    const float* ab1  = (const float*)d_in[15];
    const float* ag1  = (const float*)d_in[16];
    const float* abt1 = (const float*)d_in[17];
    const float* aw2  = (const float*)d_in[18];
    const float* ab2  = (const float*)d_in[19];
    const float* ag2  = (const float*)d_in[20];
    const float* abt2 = (const float*)d_in[21];
    float* out = (float*)d_out;

    char* ws = (char*)d_ws;
    int*   idxg   = (int*)ws;                       // 344064 B
    u16*   awp1   = (u16*)(ws + 0x54000);           // 131072 B (hi only)
    u16*   awp2   = (u16*)(ws + 0x74000);           // 262144 B (hi + lo)
    u16*   pwp2   = (u16*)(ws + 0xB4000);           // 262144 B (hi + lo)
    float* v      = (float*)(ws + 0x100000);        // 2 MB
    float* asrc   = (float*)(ws + 0x300000);        // 2 MB
    float* adst   = (float*)(ws + 0x500000);        // 2 MB
    u16*   delta  = (u16*)(ws + 0x700000);          // 22020096 B (bf16)
    u16*   alphaF = (u16*)(ws + 0x700000 + 0x1500000);  // 22020096 B (bf16)

    k_pro <<<2304,     256, 0, stream>>>(pos, x, Wl, Wsrc, Wdst, aw1, aw2, pw2,
                                         idxg, v, asrc, adst, awp1, awp2, pwp2);
    k_mlp <<<EDGES/32, 512, 0, stream>>>(pos, idxg, asrc, adst,
                                         pw1, pb1, pg1, pbt1, pwp2, pb2, pg2, pbt2,
                                         awp1, ab1, ag1, abt1, awp2, ab2, ag2, abt2,
                                         delta, alphaF);
    k_agg <<<NN/4,     256, 0, stream>>>(idxg, v, delta, alphaF, out);
}

// Round 19
// 248.663 us; speedup vs baseline: 1.1428x; 1.1428x over previous
//
#include <hip/hip_runtime.h>
#include <math.h>

#define NN    4096
#define CIN   128
#define CO    128
#define HD    512
#define KK    20
#define EE    21
#define EDGES (NN * EE)   // 86016
#define LNEPS 1e-5f
#define WSZ   65536       // elems per weight matrix (128*512)

typedef unsigned short u16;
typedef unsigned int   u32;
typedef unsigned long long u64;
typedef __attribute__((ext_vector_type(8))) short bf16x8;
typedef __attribute__((ext_vector_type(4))) float f32x4;

#define MFMA16(a,b,c) __builtin_amdgcn_mfma_f32_16x16x32_bf16(a,b,c,0,0,0)

__device__ __forceinline__ u16 f2b(float x) {
    u32 u = __float_as_uint(x);
    u32 r = u + 0x7fffu + ((u >> 16) & 1u);   // round-to-nearest-even
    return (u16)(r >> 16);
}
__device__ __forceinline__ float b2f(u16 h) {
    return __uint_as_float(((u32)h) << 16);
}
// packed 2xf32 -> 2xbf16 (RNE), 1 VALU op (no builtin on gfx950; see T12/m240)
__device__ __forceinline__ u32 cvtpk(float lo, float hi) {
    u32 r;
    asm("v_cvt_pk_bf16_f32 %0, %1, %2" : "=v"(r) : "v"(lo), "v"(hi));
    return r;
}

// ---------------- LayerNorm + ELU on bf16 rows (L=512), NW waves, cvt_pk packed ----------------
template<int L, int NW>
__device__ __forceinline__ void ln_elu_b16(u16* base, int rows, int stride,
        const float* __restrict__ gam, const float* __restrict__ bet)
{
    constexpr int P = L / 64;     // 8 contiguous elems per lane
    static_assert(P == 8, "packed path assumes P==8");
    int t = threadIdx.x, lane = t & 63, w = t >> 6;
    float g[P], b[P];
#pragma unroll
    for (int q = 0; q < P; q += 4) {
        *(float4*)&g[q] = *(const float4*)&gam[lane*P + q];
        *(float4*)&b[q] = *(const float4*)&bet[lane*P + q];
    }
    for (int e = w; e < rows; e += NW) {
        u16* row = base + e*stride + lane*P;
        uint4 rp = *(const uint4*)row;            // 1x ds_read_b128
        float vals[P];
        vals[0] = __uint_as_float(rp.x << 16); vals[1] = __uint_as_float(rp.x & 0xffff0000u);
        vals[2] = __uint_as_float(rp.y << 16); vals[3] = __uint_as_float(rp.y & 0xffff0000u);
        vals[4] = __uint_as_float(rp.z << 16); vals[5] = __uint_as_float(rp.z & 0xffff0000u);
        vals[6] = __uint_as_float(rp.w << 16); vals[7] = __uint_as_float(rp.w & 0xffff0000u);
        float s = 0.f, sq = 0.f;
#pragma unroll
        for (int q = 0; q < P; ++q) { s += vals[q]; sq = fmaf(vals[q], vals[q], sq); }
#pragma unroll
        for (int off = 32; off > 0; off >>= 1) {
            s  += __shfl_xor(s,  off, 64);
            sq += __shfl_xor(sq, off, 64);
        }
        float mn = s * (1.0f / L);
        float msq = mn * mn;
        float var = fmaf(sq, 1.0f / L, -msq);     // pinned contraction
        float rstd = rsqrtf(var + LNEPS);
        float yv[P];
#pragma unroll
        for (int q = 0; q < P; ++q) {
            float z = (vals[q] - mn) * rstd;
            float y = fmaf(z, g[q], b[q]);        // pinned
            yv[q] = y > 0.f ? y : __expf(y) - 1.f;
        }
        uint4 wp;
        wp.x = cvtpk(yv[0], yv[1]); wp.y = cvtpk(yv[2], yv[3]);
        wp.z = cvtpk(yv[4], yv[5]); wp.w = cvtpk(yv[6], yv[7]);
        *(uint4*)row = wp;                        // 1x ds_write_b128
    }
}

// ---------------- LayerNorm + ELU on f32 rows (L=128), NW waves, pinned FMA ----------------
template<int L, int NW>
__device__ __forceinline__ void ln_elu_f32v(float* base, int rows, int stride,
        const float* __restrict__ gam, const float* __restrict__ bet)
{
    constexpr int P = L / 64;     // 2
    int t = threadIdx.x, lane = t & 63, w = t >> 6;
    float g[P], b[P];
    *(float2*)&g[0] = *(const float2*)&gam[lane*P];
    *(float2*)&b[0] = *(const float2*)&bet[lane*P];
    for (int e = w; e < rows; e += NW) {
        float* row = base + e*stride + lane*P;
        float vals[P];
        *(float2*)&vals[0] = *(const float2*)&row[0];
        float s = 0.f, sq = 0.f;
#pragma unroll
        for (int q = 0; q < P; ++q) { s += vals[q]; sq = fmaf(vals[q], vals[q], sq); }
#pragma unroll
        for (int off = 32; off > 0; off >>= 1) {
            s  += __shfl_xor(s,  off, 64);
            sq += __shfl_xor(sq, off, 64);
        }
        float mn = s * (1.0f / L);
        float msq = mn * mn;
        float var = fmaf(sq, 1.0f / L, -msq);     // pinned contraction
        float rstd = rsqrtf(var + LNEPS);
#pragma unroll
        for (int q = 0; q < P; ++q) {
            float z = (vals[q] - mn) * rstd;
            float y = fmaf(z, g[q], b[q]);        // pinned
            vals[q] = y > 0.f ? y : __expf(y) - 1.f;
        }
        *(float2*)&row[0] = *(const float2*)&vals[0];
    }
}

// ---------------- fused prologue: knn (b<1024) | wconv3 (b<1792) | lin3 ----------------
__global__ __launch_bounds__(256) void k_pro(
        const float* __restrict__ pos, const float* __restrict__ x,
        const float* __restrict__ Wl, const float* __restrict__ Ws, const float* __restrict__ Wd,
        const float* __restrict__ aw1, const float* __restrict__ aw2,
        const float* __restrict__ pw2,
        int* __restrict__ idxg, float* __restrict__ v,
        float* __restrict__ as_, float* __restrict__ ad,
        u16* __restrict__ awp1, u16* __restrict__ awp2, u16* __restrict__ pwp2)
{
    __shared__ float sx[8][CIN];
    int b = blockIdx.x;
    if (b < 1024) {                 // ---- kNN: 4 nodes/block, 1 wave each ----
        int i = b * 4 + (threadIdx.x >> 6);
        int lane = threadIdx.x & 63;
        float px = pos[3*i], py = pos[3*i+1], pz = pos[3*i+2];
        float bd[KK]; int bi[KK];
#pragma unroll
        for (int s = 0; s < KK; ++s) { bd[s] = INFINITY; bi[s] = 0x7fffffff; }
        for (int j = lane; j < NN; j += 64) {
            float dx = px - pos[3*j], dy = py - pos[3*j+1], dz = pz - pos[3*j+2];
            float d2 = dx*dx + dy*dy + dz*dz;
            if (j != i && d2 < bd[KK-1]) {
                float cd = d2; int ci = j;
#pragma unroll
                for (int s = 0; s < KK; ++s) {   // static-index bubble insert
                    bool sw = cd < bd[s];
                    float td = sw ? bd[s] : cd;  int ti = sw ? bi[s] : ci;
                    bd[s] = sw ? cd : bd[s];     bi[s] = sw ? ci : bi[s];
                    cd = td; ci = ti;
                }
            }
        }
        for (int r = 0; r < KK; ++r) {
            u64 m = ~0ull;
#pragma unroll
            for (int s = 0; s < KK; ++s) {
                u64 k = ((u64)__float_as_uint(bd[s]) << 32) | (u32)bi[s];
                m = k < m ? k : m;
            }
#pragma unroll
            for (int off = 32; off > 0; off >>= 1) {
                u64 o = __shfl_xor(m, off, 64);
                m = o < m ? o : m;
            }
            if (lane == 0) idxg[i*EE + r] = (int)(u32)m;
#pragma unroll
            for (int s = 0; s < KK; ++s) {
                u64 k = ((u64)__float_as_uint(bd[s]) << 32) | (u32)bi[s];
                if (k == m) bd[s] = INFINITY;
            }
        }
        if (lane == 0) idxg[i*EE + KK] = i;   // self-loop appended
    } else if (b < 1792) {          // ---- weight prepack ----
        int gb = b - 1024;
        const float* src; u16* dst; int N, kplog, base; bool split;
        if (gb < 256)      { src = aw1; dst = awp1; N = HD; kplog = 2; base = 0;   split = false; }
        else if (gb < 512) { src = aw2; dst = awp2; N = CO; kplog = 4; base = 256; split = true;  }
        else               { src = pw2; dst = pwp2; N = CO; kplog = 4; base = 512; split = true;  }
        int idx = (gb - base)*256 + threadIdx.x;
        int j  = idx & 7;
        int l  = (idx >> 3) & 63;
        int ks = (idx >> 9) & ((1 << kplog) - 1);
        int nt = idx >> (9 + kplog);
        int k = ks*32 + (l >> 4)*8 + j;
        int c = nt*16 + (l & 15);
        float w = src[(size_t)k*N + c];
        u16 hi = f2b(w);
        dst[idx] = hi;
        if (split) dst[idx + WSZ] = f2b(w - b2f(hi));
    } else {                        // ---- lin3: v / a_src / a_dst, 8 nodes/block ----
        int bb = b - 1792, t = threadIdx.x;
        int n0 = bb * 8;
        for (int q = t; q < 8*CIN; q += 256) sx[q >> 7][q & 127] = x[n0*CIN + q];
        __syncthreads();
        int c = t & 127, g = t >> 7;
        float al[4] = {0,0,0,0}, asr[4] = {0,0,0,0}, adr[4] = {0,0,0,0};
        for (int k = 0; k < CIN; ++k) {
            float wl = Wl[k*CO + c], ws = Ws[k*CO + c], wd = Wd[k*CO + c];
#pragma unroll
            for (int nn2 = 0; nn2 < 4; ++nn2) {
                float xv = sx[g*4 + nn2][k];
                al[nn2]  = fmaf(xv, wl, al[nn2]);
                asr[nn2] = fmaf(xv, ws, asr[nn2]);
                adr[nn2] = fmaf(xv, wd, adr[nn2]);
            }
        }
#pragma unroll
        for (int nn2 = 0; nn2 < 4; ++nn2) {
            int n = n0 + g*4 + nn2;
            v[n*CO + c]   = al[nn2];
            as_[n*CO + c] = asr[nn2];
            ad[n*CO + c]  = adr[nn2];
        }
    }
}

// strides (padded)
#define SA_S 136   // u16, 128+8
#define SH_S 520   // u16, 512+8
#define SF_S 132   // f32, 128+4

// ---------------- fused MLP: pos_nn -> delta -> alpha0 -> attn_nn (32 edges/block) ----------------
__global__ __launch_bounds__(512) void k_mlp(
        const float* __restrict__ pos, const int* __restrict__ idxg,
        const float* __restrict__ as_, const float* __restrict__ ad,
        const float* __restrict__ pw1, const float* __restrict__ pb1,
        const float* __restrict__ pg1, const float* __restrict__ pbt1,
        const u16* __restrict__ pwp2, const float* __restrict__ pb2,
        const float* __restrict__ pg2, const float* __restrict__ pbt2,
        const u16* __restrict__ awp1, const float* __restrict__ ab1,
        const float* __restrict__ ag1, const float* __restrict__ abt1,
        const u16* __restrict__ awp2, const float* __restrict__ ab2,
        const float* __restrict__ ag2, const float* __restrict__ abt2,
        u16* __restrict__ delta, u16* __restrict__ alphaF)
{
    // s_h (33280 B) phases: P1 h -> [rows 0..8 reused for alpha0] -> A1 h
    // s_u (16896 B) phases: posnn f32 delta -> A2 f32 alphaF
    __shared__ __align__(16) u16   s_h[32*SH_S];     // 33280 B
    __shared__ __align__(16) float s_u[32*SF_S];     // 16896 B union region
    float* s_d  = s_u;
    float* s_af = s_u;
    u16*   s_aH = s_h;          // alpha0 staged over s_h rows 0..8 (SA_S stride)
    __shared__ float s_rel[32][3];
    int t = threadIdx.x;
    int e0g = blockIdx.x * 32;
    if (t < 32) {
        int e = e0g + t;
        u32 ii = (u32)e / 21u;
        int j = idxg[e];
        s_rel[t][0] = pos[3*ii]   - pos[3*j];
        s_rel[t][1] = pos[3*ii+1] - pos[3*j+1];
        s_rel[t][2] = pos[3*ii+2] - pos[3*j+2];
    }
    __syncthreads();
    {   // P1: h = rel @ pw1 + pb1 (pinned fmaf chain; 1 channel/thread, row pairs via cvt_pk)
        int c1 = t;
        float wa0 = pw1[c1], wa1 = pw1[HD + c1], wa2 = pw1[2*HD + c1], ba = pb1[c1];
        for (int r = 0; r < 32; r += 2) {
            float h0 = fmaf(s_rel[r][2],   wa2, fmaf(s_rel[r][1],   wa1, fmaf(s_rel[r][0],   wa0, ba)));
            float h1 = fmaf(s_rel[r+1][2], wa2, fmaf(s_rel[r+1][1], wa1, fmaf(s_rel[r+1][0], wa0, ba)));
            u32 pk = cvtpk(h0, h1);
            s_h[r*SH_S + c1]     = (u16)pk;
            s_h[(r+1)*SH_S + c1] = (u16)(pk >> 16);
        }
    }
    __syncthreads();
    ln_elu_b16<HD, 8>(s_h, 32, SH_S, pg1, pbt1);
    __syncthreads();
    int w = t >> 6, l = t & 63, lr = l & 15, lk = l >> 4;
    {   // P2 (MFMA, split-weight, dual acc): 8 waves x 2 n-tiles -> s_d (f32)
        int m = w & 1, nt0 = (w >> 1) * 2;
        bf16x8 afr[16];
#pragma unroll
        for (int ks = 0; ks < 16; ++ks)
            afr[ks] = *(const bf16x8*)&s_h[(m*16 + lr)*SH_S + ks*32 + lk*8];
#pragma unroll
        for (int n2 = 0; n2 < 2; ++n2) {
            int nt = nt0 + n2;
            const u16* bp  = pwp2 + ((size_t)nt*16*64 + l)*8;
            const u16* bpl = bp + WSZ;
            f32x4 acch = {0.f, 0.f, 0.f, 0.f};
            f32x4 accl = {0.f, 0.f, 0.f, 0.f};
#pragma unroll
            for (int ks = 0; ks < 16; ++ks) {
                bf16x8 bh = *(const bf16x8*)(bp + ks*512);
                acch = MFMA16(afr[ks], bh, acch);
                bf16x8 bl = *(const bf16x8*)(bpl + ks*512);
                accl = MFMA16(afr[ks], bl, accl);
            }
            float bias = pb2[nt*16 + lr];
#pragma unroll
            for (int r = 0; r < 4; ++r)
                s_d[(m*16 + lk*4 + r)*SF_S + nt*16 + lr] = (acch[r] + accl[r]) + bias;
        }
    }
    __syncthreads();
    ln_elu_f32v<CO, 8>(s_d, 32, SF_S, pg2, pbt2);
    __syncthreads();
    {   // delta store (bf16, cvt_pk) + alpha0 = ad[i] - as[j] + delta_f32 -> s_aH
        int el = t >> 4, c0 = (t & 15) << 3;
        int e = e0g + el;
        int i = (int)((u32)e / 21u);
        int j = idxg[e];
        const float* sp  = &s_d[el*SF_S + c0];
        float4 d0 = *(const float4*)(sp);
        float4 d1 = *(const float4*)(sp + 4);
        uint4 od;
        od.x = cvtpk(d0.x, d0.y); od.y = cvtpk(d0.z, d0.w);
        od.z = cvtpk(d1.x, d1.y); od.w = cvtpk(d1.z, d1.w);
        *(uint4*)&delta[(size_t)e*CO + c0] = od;
        const float* adp = ad  + i*CIN + c0;
        const float* asp = as_ + j*CIN + c0;
        float4 a0 = *(const float4*)(adp);
        float4 a1 = *(const float4*)(adp + 4);
        float4 s0 = *(const float4*)(asp);
        float4 s1 = *(const float4*)(asp + 4);
        uint4 oa;
        oa.x = cvtpk(a0.x - s0.x + d0.x, a0.y - s0.y + d0.y);
        oa.y = cvtpk(a0.z - s0.z + d0.z, a0.w - s0.w + d0.w);
        oa.z = cvtpk(a1.x - s1.x + d1.x, a1.y - s1.y + d1.y);
        oa.w = cvtpk(a1.z - s1.z + d1.z, a1.w - s1.w + d1.w);
        *(uint4*)&s_aH[el*SA_S + c0] = oa;
    }
    __syncthreads();
    // A1 fragment loads (alpha0 lives in s_h rows 0..8 -> load BEFORE A1 writes s_h)
    bf16x8 afr1[4];
    {
        int m = w & 1;
#pragma unroll
        for (int ks = 0; ks < 4; ++ks)
            afr1[ks] = *(const bf16x8*)&s_aH[(m*16 + lr)*SA_S + ks*32 + lk*8];
    }
    __syncthreads();   // all waves hold alpha0 fragments; s_h now writable
    {   // A1 (MFMA): [32,128]@[128,512]; 8 waves x 8 n-tiles -> s_h (bf16, cvt_pk pairs)
        int m = w & 1, nt0 = (w >> 1) * 8;
#pragma unroll
        for (int n2 = 0; n2 < 8; ++n2) {
            int nt = nt0 + n2;
            const u16* bp = awp1 + ((size_t)nt*4*64 + l)*8;
            f32x4 acc = {0.f, 0.f, 0.f, 0.f};
#pragma unroll
            for (int ks = 0; ks < 4; ++ks) {
                bf16x8 bfr = *(const bf16x8*)(bp + ks*512);
                acc = MFMA16(afr1[ks], bfr, acc);
            }
            float bias = ab1[nt*16 + lr];
            u32 p01 = cvtpk(acc[0] + bias, acc[1] + bias);
            u32 p23 = cvtpk(acc[2] + bias, acc[3] + bias);
            int rb = (m*16 + lk*4)*SH_S + nt*16 + lr;
            s_h[rb]          = (u16)p01;
            s_h[rb + SH_S]   = (u16)(p01 >> 16);
            s_h[rb + 2*SH_S] = (u16)p23;
            s_h[rb + 3*SH_S] = (u16)(p23 >> 16);
        }
    }
    __syncthreads();
    ln_elu_b16<HD, 8>(s_h, 32, SH_S, ag1, abt1);
    __syncthreads();
    {   // A2 (MFMA, split-weight, dual acc): 8 waves x 2 n-tiles -> s_af (f32)
        int m = w & 1, nt0 = (w >> 1) * 2;
        bf16x8 afr[16];
#pragma unroll
        for (int ks = 0; ks < 16; ++ks)
            afr[ks] = *(const bf16x8*)&s_h[(m*16 + lr)*SH_S + ks*32 + lk*8];
#pragma unroll
        for (int n2 = 0; n2 < 2; ++n2) {
            int nt = nt0 + n2;
            const u16* bp  = awp2 + ((size_t)nt*16*64 + l)*8;
            const u16* bpl = bp + WSZ;
            f32x4 acch = {0.f, 0.f, 0.f, 0.f};
            f32x4 accl = {0.f, 0.f, 0.f, 0.f};
#pragma unroll
            for (int ks = 0; ks < 16; ++ks) {
                bf16x8 bh = *(const bf16x8*)(bp + ks*512);
                acch = MFMA16(afr[ks], bh, acch);
                bf16x8 bl = *(const bf16x8*)(bpl + ks*512);
                accl = MFMA16(afr[ks], bl, accl);
            }
            float bias = ab2[nt*16 + lr];
#pragma unroll
            for (int r = 0; r < 4; ++r)
                s_af[(m*16 + lk*4 + r)*SF_S + nt*16 + lr] = (acch[r] + accl[r]) + bias;
        }
    }
    __syncthreads();
    ln_elu_f32v<CO, 8>(s_af, 32, SF_S, ag2, abt2);
    __syncthreads();
    {   // store alphaF: cvt_pk at the end only
        int el = t >> 4, c0 = (t & 15) << 3;
        const float* sp = &s_af[el*SF_S + c0];
        float4 v0 = *(const float4*)(sp);
        float4 v1 = *(const float4*)(sp + 4);
        uint4 o;
        o.x = cvtpk(v0.x, v0.y); o.y = cvtpk(v0.z, v0.w);
        o.z = cvtpk(v1.x, v1.y); o.w = cvtpk(v1.z, v1.w);
        *(uint4*)&alphaF[(size_t)(e0g + el)*CO + c0] = o;
    }
}

// ---------------- softmax over neighbors + weighted aggregate (4 nodes/block, 2 ch/thread) ----------------
__global__ __launch_bounds__(256) void k_agg(
        const int* __restrict__ idxg,
        const float* __restrict__ v, const u16* __restrict__ delta,
        const u16* __restrict__ alphaF, float* __restrict__ out)
{
    __shared__ int s_idx[4][EE];
    int b = blockIdx.x, t = threadIdx.x;
    int n0 = b * 4;
    if (t < 4*EE) s_idx[t/EE][t%EE] = idxg[n0*EE + t];
    __syncthreads();
    int g = t >> 6, c0 = (t & 63) * 2;
    int i = n0 + g;
    size_t base = (size_t)i*EE*CO + c0;
    float afx[EE], afy[EE];
    float mx0 = -INFINITY, mx1 = -INFINITY;
#pragma unroll
    for (int e = 0; e < EE; ++e) {
        ushort2 u = *(const ushort2*)&alphaF[base + e*CO];
        afx[e] = b2f(u.x); afy[e] = b2f(u.y);
        mx0 = fmaxf(mx0, afx[e]); mx1 = fmaxf(mx1, afy[e]);
    }
    float ss0 = 0.f, ss1 = 0.f;
#pragma unroll
    for (int e = 0; e < EE; ++e) {
        afx[e] = __expf(afx[e] - mx0); ss0 += afx[e];
        afy[e] = __expf(afy[e] - mx1); ss1 += afy[e];
    }
    float ac0 = 0.f, ac1 = 0.f;
#pragma unroll
    for (int e = 0; e < EE; ++e) {
        int j = s_idx[g][e];
        float2 vv = *(const float2*)&v[j*CO + c0];
        ushort2 dd = *(const ushort2*)&delta[base + e*CO];
        ac0 = fmaf(afx[e], vv.x + b2f(dd.x), ac0);
        ac1 = fmaf(afy[e], vv.y + b2f(dd.y), ac1);
    }
    float2 o; o.x = ac0 / ss0; o.y = ac1 / ss1;
    *(float2*)&out[i*CO + c0] = o;
}

extern "C" void kernel_launch(void* const* d_in, const int* in_sizes, int n_in,
                              void* d_out, int out_size, void* d_ws, size_t ws_size,
                              hipStream_t stream)
{
    const float* x    = (const float*)d_in[0];
    const float* pos  = (const float*)d_in[1];
    const float* Wl   = (const float*)d_in[3];
    const float* Wsrc = (const float*)d_in[4];
    const float* Wdst = (const float*)d_in[5];
    const float* pw1  = (const float*)d_in[6];
    const float* pb1  = (const float*)d_in[7];
    const float* pg1  = (const float*)d_in[8];
    const float* pbt1 = (const float*)d_in[9];
    const float* pw2  = (const float*)d_in[10];
    const float* pb2  = (const float*)d_in[11];
    const float* pg2  = (const float*)d_in[12];
    const float* pbt2 = (const float*)d_in[13];
    const float* aw1  = (const float*)d_in[14];
    const float* ab1  = (const float*)d_in[15];
    const float* ag1  = (const float*)d_in[16];
    const float* abt1 = (const float*)d_in[17];
    const float* aw2  = (const float*)d_in[18];
    const float* ab2  = (const float*)d_in[19];
    const float* ag2  = (const float*)d_in[20];
    const float* abt2 = (const float*)d_in[21];
    float* out = (float*)d_out;

    char* ws = (char*)d_ws;
    int*   idxg   = (int*)ws;                       // 344064 B
    u16*   awp1   = (u16*)(ws + 0x54000);           // 131072 B (hi only)
    u16*   awp2   = (u16*)(ws + 0x74000);           // 262144 B (hi + lo)
    u16*   pwp2   = (u16*)(ws + 0xB4000);           // 262144 B (hi + lo)
    float* v      = (float*)(ws + 0x100000);        // 2 MB
    float* asrc   = (float*)(ws + 0x300000);        // 2 MB
    float* adst   = (float*)(ws + 0x500000);        // 2 MB
    u16*   delta  = (u16*)(ws + 0x700000);          // 22020096 B (bf16)
    u16*   alphaF = (u16*)(ws + 0x700000 + 0x1500000);  // 22020096 B (bf16)

    k_pro <<<2304,     256, 0, stream>>>(pos, x, Wl, Wsrc, Wdst, aw1, aw2, pw2,
                                         idxg, v, asrc, adst, awp1, awp2, pwp2);
    k_mlp <<<EDGES/32, 512, 0, stream>>>(pos, idxg, asrc, adst,
                                         pw1, pb1, pg1, pbt1, pwp2, pb2, pg2, pbt2,
                                         awp1, ab1, ag1, abt1, awp2, ab2, ag2, abt2,
                                         delta, alphaF);
    k_agg <<<NN/4,     256, 0, stream>>>(idxg, v, delta, alphaF, out);
}